// Round 4
// baseline (2981.301 us; speedup 1.0000x reference)
//
#include <hip/hip_runtime.h>
#include <cstdint>
#include <cstddef>

// B=32, S=512, I=256, H=512, E=1024, NH=16, HD=64
// Structural collapse (verified): only attention head 15 at s in [496,512)
// reaches the FC head; backward LSTM needs only its first 16 steps; Wo/Wfc
// fold to w_eff; w_eff-contracted Wv folds to wv2.
//
// Round 5: back to the 1853us 128-WG topology (XCD-local sc0 experiment
// regressed to 2133us: sc0 fast-leg never paid, every-4th agent check +
// sleeps added ~1000cyc/step). ONE change vs baseline: the h-exchange is now
// a monotonic per-producer-wave FLAG handshake instead of data-sentinel
// polling. Producer: AT_ST h -> s_waitcnt vmcnt(0) -> AT_ST flag=t+1 (fixed
// hot address). Consumer: each gather thread's 32B slice depends on exactly
// one producer wave -> poll one 4B flag >= t, then ONE-shot data load.
// Removes per-step cold-HBM sentinel-line fetches (FETCH_SIZE was 99MB) and
// the 32768-thread x 32B coherent poll storm. Sentinel check kept as a
// never-taken safety retry.

typedef _Float16 v8h __attribute__((ext_vector_type(8)));
typedef _Float16 v4h __attribute__((ext_vector_type(4)));
typedef float    v4f __attribute__((ext_vector_type(4)));

#define AT_LD(p)     __hip_atomic_load((p), __ATOMIC_RELAXED, __HIP_MEMORY_SCOPE_AGENT)
#define AT_ST(p, v)  __hip_atomic_store((p), (v), __ATOMIC_RELAXED, __HIP_MEMORY_SCOPE_AGENT)

// ---- workspace layout (bytes) ----
static constexpr size_t OFF_CNT   = 0;        // 3 x u32: lstm-done, -, epi-done
static constexpr size_t OFF_LOGIT = 256;      // 32 f32
static constexpr size_t OFF_BEFF  = 512;      // 1 f32
static constexpr size_t OFF_WEFF  = 1024;     // 1024 f32 (ends 5120)
static constexpr size_t OFF_FLGF  = 5632;     // fwd flags: 4 groups x 64 u32
static constexpr size_t OFF_FLGB  = 6656;     // bwd flags: 4 groups x 64 u32
static constexpr size_t OFF_HF    = 8192;     // h_f[513][32][512] f16 (slot = s+1)
static constexpr size_t HF_BYTES  = 513ull*32768;
static constexpr size_t OFF_HB    = OFF_HF + HF_BYTES;   // h_b[17][32][512] f16
static constexpr size_t HB_BYTES  = 17ull*32768;
static constexpr size_t OFF_WHHF  = OFF_HB + HB_BYTES;   // 2048x512 f16
static constexpr size_t OFF_WIHF  = OFF_WHHF + 2048ull*512*2;
static constexpr size_t OFF_WHHB  = OFF_WIHF + 2048ull*256*2;
static constexpr size_t OFF_WIHB  = OFF_WHHB + 2048ull*512*2;
static constexpr size_t OFF_WKT   = OFF_WIHB + 2048ull*256*2;   // 1024x1024 f16
static constexpr size_t OFF_WQT   = OFF_WKT + 1024ull*1024*2;   // 1024x64 f16
static constexpr size_t OFF_WV2   = OFF_WQT + 1024ull*64*2;     // 16*1024*16 f32
static constexpr size_t OFF_CV    = OFF_WV2 + 16ull*1024*16*4;  // 256 f32
// total ~25.7 MiB

static constexpr int PSTR    = 776;                 // panel stride (f16)
static constexpr int GSTR    = 68;                  // gates stride (f32)
static constexpr int LDS_PANEL_B = 16*PSTR*2;       // 24832
static constexpr int DYN_LDS = LDS_PANEL_B + 64*GSTR*4;  // 24832+17408 = 42240

__device__ __forceinline__ bool has_ffff(unsigned long long w) {
    return ((w & 0xFFFFull) == 0xFFFFull) ||
           (((w >> 16) & 0xFFFFull) == 0xFFFFull) ||
           (((w >> 32) & 0xFFFFull) == 0xFFFFull) ||
           ((w >> 48) == 0xFFFFull);
}

// -------------------- prep kernels --------------------

__global__ void k_convert(const float* __restrict__ whhf, const float* __restrict__ wihf,
                          const float* __restrict__ whhb, const float* __restrict__ wihb,
                          char* __restrict__ ws)
{
    _Float16* o1 = (_Float16*)(ws + OFF_WHHF);
    _Float16* o2 = (_Float16*)(ws + OFF_WIHF);
    _Float16* o3 = (_Float16*)(ws + OFF_WHHB);
    _Float16* o4 = (_Float16*)(ws + OFF_WIHB);
    const int stride = gridDim.x * blockDim.x;
    for (int i = blockIdx.x*blockDim.x + threadIdx.x; i < 2048*512; i += stride) {
        o1[i] = (_Float16)whhf[i];
        o3[i] = (_Float16)whhb[i];
    }
    for (int i = blockIdx.x*blockDim.x + threadIdx.x; i < 2048*256; i += stride) {
        o2[i] = (_Float16)wihf[i];
        o4[i] = (_Float16)wihb[i];
    }
}

// weff[e2] += partial(Wfc . Wo[:,e2]); beff += partial(Wfc . bo) (+bfc once)
__global__ void k_weff(const float* __restrict__ Wfc, const float* __restrict__ Wo,
                       const float* __restrict__ bo, const float* __restrict__ bfc,
                       char* __restrict__ ws)
{
    float* weff = (float*)(ws + OFF_WEFF);
    float* beff = (float*)(ws + OFF_BEFF);
    const int bid = blockIdx.x;                 // 64 blocks
    const int e2 = (bid & 3)*256 + threadIdx.x;
    const int slab = bid >> 2;                  // 16 slabs of 64 e
    float a = 0.f;
    for (int e = slab*64; e < slab*64 + 64; ++e)
        a += Wfc[e] * Wo[(size_t)e*1024 + e2];
    atomicAdd(weff + e2, a);
    if ((bid & 3) == 0 && threadIdx.x < 64) {
        const int e = slab*64 + threadIdx.x;
        float b = Wfc[e]*bo[e];
        if (bid == 0 && threadIdx.x == 0) b += bfc[0];
        atomicAdd(beff, b);
    }
}

// wv2[(r*1024+e)*16+kh] = sum_hd weff[r*64+hd]*Wv[(kh*64+hd)*1024+e]; cv
__global__ void k_wv2(const float* __restrict__ Wv, const float* __restrict__ bv,
                      char* __restrict__ ws)
{
    const float* weff = (const float*)(ws + OFF_WEFF);
    float* wv2 = (float*)(ws + OFF_WV2);
    float* cv  = (float*)(ws + OFF_CV);
    const int bid = blockIdx.x;                 // 65 blocks
    if (bid < 64) {
        const int r = bid >> 2;
        const int e = (bid & 3)*256 + threadIdx.x;
        for (int kh = 0; kh < 16; ++kh) {
            float a = 0.f;
            for (int hd = 0; hd < 64; ++hd)
                a += weff[r*64 + hd] * Wv[((size_t)(kh*64 + hd))*1024 + e];
            wv2[((size_t)r*1024 + e)*16 + kh] = a;
        }
    } else {
        const int r2 = threadIdx.x >> 4, k2 = threadIdx.x & 15;
        float a = 0.f;
        for (int hd = 0; hd < 64; ++hd)
            a += weff[r2*64 + hd] * bv[k2*64 + hd];
        cv[threadIdx.x] = a;
    }
}

// WkT[e][j] = Wk[j][e], fp16
__global__ void k_tk(const float* __restrict__ Wk, char* __restrict__ ws)
{
    _Float16* WkT = (_Float16*)(ws + OFF_WKT);
    __shared__ float tile[32][33];
    const int jt = blockIdx.x & 31, et = blockIdx.x >> 5;   // 1024 blocks
    const int tx = threadIdx.x & 31, ty = threadIdx.x >> 5; // 32x8
    for (int i = 0; i < 4; ++i)
        tile[ty + 8*i][tx] = Wk[((size_t)(jt*32 + ty + 8*i))*1024 + et*32 + tx];
    __syncthreads();
    for (int i = 0; i < 4; ++i)
        WkT[((size_t)(et*32 + ty + 8*i))*1024 + jt*32 + tx] = (_Float16)tile[tx][ty + 8*i];
}

// WqT15[e][d] = Wq[960+d][e], fp16
__global__ void k_tq(const float* __restrict__ Wq, char* __restrict__ ws)
{
    _Float16* WqT = (_Float16*)(ws + OFF_WQT);
    const int gid = blockIdx.x*256 + threadIdx.x;  // 256 blocks
    const int d = gid & 63, e = gid >> 6;
    WqT[e*64 + d] = (_Float16)Wq[((size_t)(960 + d))*1024 + e];
}

// -------------------- main persistent kernel --------------------
// 128 WGs x 256 threads. group g = wgid>>5 (8 batches), colgroup = wgid&31
// (16 h-cols). Phase 0: bwd 16 steps; phase 1: fwd 512 steps.
// Flag handshake: flag[dir][g][cg*2+w] = #slots published by producer wave w
// of col-WG cg. Consumer thread (b,seg) polls exactly flag[seg*2 + (b>>2)].

__global__ __launch_bounds__(256, 1)
void bilstm_main(const float* __restrict__ xg,
                 const float* __restrict__ b_f, const float* __restrict__ b_b,
                 const float* __restrict__ bq,  const float* __restrict__ bk,
                 char* __restrict__ ws, float* __restrict__ out)
{
    extern __shared__ char smem[];
    _Float16* panel = (_Float16*)smem;                   // [16][776]
    float* gates = (float*)(smem + LDS_PANEL_B);         // [64][68]

    const int tid  = threadIdx.x;
    const int wgid = blockIdx.x;
    const int wave = tid >> 6;
    const int lane = tid & 63;
    const int quad = lane >> 4;
    const int l16  = lane & 15;
    const int grp  = wgid >> 5;            // batch group (8 batches)
    const int col0 = (wgid & 31) * 16;

    unsigned* cnts  = (unsigned*)(ws + OFF_CNT);
    float*   logits = (float*)(ws + OFF_LOGIT);

    // activation role (tid < 128): batch b = tid>>4 in [0,8), col c = tid&15
    const int ac = tid & 15;
    const int ab = tid >> 4;

    for (int phase = 0; phase < 2; ++phase) {
        const int dir     = phase == 0 ? 1 : 0;       // bwd first
        const int nsteps  = dir ? 16 : 512;
        char* hslab = ws + (dir ? OFF_HB : OFF_HF);
        const _Float16* whh = (const _Float16*)(ws + (dir ? OFF_WHHB : OFF_WHHF));
        const _Float16* wih = (const _Float16*)(ws + (dir ? OFF_WIHB : OFF_WIHF));
        const float* bias = dir ? b_b : b_f;
        unsigned* flg = (unsigned*)(ws + (dir ? OFF_FLGB : OFF_FLGF)) + grp*64;

        // persistent B fragments: rows (gate nt, col l16) x K=768, wave = K-quarter
        v8h bfrag[4][6];
#pragma unroll
        for (int nt = 0; nt < 4; ++nt)
#pragma unroll
            for (int kk = 0; kk < 6; ++kk) {
                const int kb = (wave*6 + kk)*32 + quad*8;
                const int r  = nt*512 + col0 + l16;
                const _Float16* src = (kb < 512) ? (whh + (size_t)r*512 + kb)
                                                 : (wih + (size_t)r*256 + (kb - 512));
                bfrag[nt][kk] = *(const v8h*)src;
            }
        float bia[4];
#pragma unroll
        for (int g = 0; g < 4; ++g) bia[g] = bias[g*512 + col0 + ac];

        float cst = 0.f;

        for (int t = 0; t < nsteps; ++t) {
            const int s = dir ? (511 - t) : t;

            // prefetch x[group batches][s][:] into registers
            float4 xv[2];
#pragma unroll
            for (int i = 0; i < 2; ++i) {
                const int ch = tid + 256*i;           // [0,512)
                const int b = ch >> 6, ic = ch & 63;
                xv[i] = *(const float4*)(xg + ((size_t)(grp*8 + b)*512 + s)*256 + ic*4);
            }

            // gather h_{t-1} (slot t): flag-wait, then one-shot data load.
            {
                const int b = tid >> 5, seg = tid & 31;   // 8 KB: 8 b x 512 cols
                // producer of this 32B slice: col-WG 'seg', wave (b>>2)
                const unsigned* fp = flg + seg*2 + (b >> 2);
                while (AT_LD(fp) < (unsigned)t)
                    __builtin_amdgcn_s_sleep(1);
                asm volatile("" ::: "memory");   // pin data loads after flag
                const unsigned long long* src = (const unsigned long long*)hslab
                    + (size_t)t*4096 + (size_t)(grp*8 + b)*128 + seg*4;
                unsigned long long w0, w1, w2, w3;
                for (;;) {
                    w0 = AT_LD(src + 0); w1 = AT_LD(src + 1);
                    w2 = AT_LD(src + 2); w3 = AT_LD(src + 3);
                    if (!(has_ffff(w0) || has_ffff(w1) || has_ffff(w2) || has_ffff(w3)))
                        break;   // flag guarantees this on first pass
                    __builtin_amdgcn_s_sleep(1);
                }
                unsigned long long* dst = (unsigned long long*)(panel + b*PSTR + seg*16);
                dst[0] = w0; dst[1] = w1; dst[2] = w2; dst[3] = w3;
            }
            // x (f32 regs -> f16) into panel cols [512,768)
#pragma unroll
            for (int i = 0; i < 2; ++i) {
                const int ch = tid + 256*i;
                const int b = ch >> 6, ic = ch & 63;
                v4h hx = { (_Float16)xv[i].x, (_Float16)xv[i].y,
                           (_Float16)xv[i].z, (_Float16)xv[i].w };
                *(v4h*)(panel + b*PSTR + 512 + ic*4) = hx;
            }
            __syncthreads();   // S_a: panel ready

            // GEMM: gates[b(8)][n(64)] = A[b][768] * W[n][768], K 4-way by wave
            v4f acc[4];
#pragma unroll
            for (int nt = 0; nt < 4; ++nt) { v4f z = {0.f,0.f,0.f,0.f}; acc[nt] = z; }
#pragma unroll
            for (int kk = 0; kk < 6; ++kk) {
                const int kb = (wave*6 + kk)*32 + quad*8;
                const v8h a0 = *(const v8h*)(panel + l16*PSTR + kb);
#pragma unroll
                for (int nt = 0; nt < 4; ++nt)
                    acc[nt] = __builtin_amdgcn_mfma_f32_16x16x32_f16(a0, bfrag[nt][kk], acc[nt], 0, 0, 0);
            }
            // K-partials (separate LDS region; panel reads complete before S_c)
#pragma unroll
            for (int nt = 0; nt < 4; ++nt)
#pragma unroll
                for (int r = 0; r < 4; ++r)
                    gates[(nt*16 + l16)*GSTR + (quad*4 + r)*4 + wave] = acc[nt][r];
            __syncthreads();   // S_c: partials ready

            // activations: tid<128, one (b, c) each
            if (tid < 128) {
                float g[4];
#pragma unroll
                for (int gi = 0; gi < 4; ++gi) {
                    const v4f v = *(const v4f*)(gates + (gi*16 + ac)*GSTR + ab*4);
                    g[gi] = v.x + v.y + v.z + v.w + bia[gi];
                }
                const float ig = 1.f/(1.f + __expf(-g[0]));
                const float fg = 1.f/(1.f + __expf(-g[1]));
                const float gg = 1.f - 2.f/(__expf(2.f*g[2]) + 1.f);
                const float og = 1.f/(1.f + __expf(-g[3]));
                cst = fg*cst + ig*gg;
                const float hn = og * (1.f - 2.f/(__expf(2.f*cst) + 1.f));
                const unsigned hb = (unsigned)__builtin_bit_cast(unsigned short, (_Float16)hn);
                const unsigned ot = (unsigned)__shfl_xor((int)hb, 1);
                if ((ac & 1) == 0) {
                    _Float16* hrow = (_Float16*)hslab
                        + ((size_t)(t+1)*32 + (grp*8 + ab))*512 + col0 + ac;
                    AT_ST((unsigned*)hrow, hb | (ot << 16));
                }
                // publish: drain this wave's h stores to the coherence point,
                // then bump the wave's monotone flag (slot t+1 available).
                asm volatile("s_waitcnt vmcnt(0)" ::: "memory");
                if ((tid & 63) == 0)
                    AT_ST(flg + (wgid & 31)*2 + (tid >> 6), (unsigned)(t + 1));
            }
            // no trailing barrier: next step's flag-wait self-synchronizes
        }
    }

    // join before epilogue
    __syncthreads();
    if (tid == 0) {
        __hip_atomic_fetch_add(cnts + 0, 1u, __ATOMIC_RELEASE, __HIP_MEMORY_SCOPE_AGENT);
        while (AT_LD(cnts + 0) < 128u) __builtin_amdgcn_s_sleep(8);
    }
    __syncthreads();

    // ---------------- collapsed attention epilogue ----------------
    // 4 pairs per WG: p = wgid*4+pp -> (b = p>>4, r = p&15, s' = 496+r)
    float*    hv  = (float*)smem;                 // [4][1024]
    _Float16* k16 = (_Float16*)(smem + 16384);    // [4][1024]
    float*    qb  = (float*)(smem + 24576);       // [4][64]
    float*    vzb = (float*)(smem + 25600);       // [4][16]
    float*    scb = (float*)(smem + 25856);       // [4][16]
    int*      lastf = (int*)(smem + 26112);

    const _Float16* WkT = (const _Float16*)(ws + OFF_WKT);
    const _Float16* WqT = (const _Float16*)(ws + OFF_WQT);
    const float* wv2 = (const float*)(ws + OFF_WV2);
    const float* cv  = (const float*)(ws + OFF_CV);
    const float* beff= (const float*)(ws + OFF_BEFF);

    const int p0 = wgid * 4;
#pragma unroll
    for (int i = 0; i < 4; ++i) {
        const int ch = tid + 256*i;               // 1024 u64 chunks
        const int pp = ch >> 8, q = ch & 255;     // e = q*4
        const int p = p0 + pp; const int b = p >> 4; const int r = p & 15;
        unsigned long long w;
        if (q < 128)   // fwd h at s=496+r -> slot 497+r
            w = AT_LD((const unsigned long long*)(ws + OFF_HF)
                      + ((size_t)(497 + r)*32 + b)*128 + q);
        else           // bwd h at s=496+r -> slot 16-r
            w = AT_LD((const unsigned long long*)(ws + OFF_HB)
                      + ((size_t)(16 - r)*32 + b)*128 + (q - 128));
        float* dst = hv + pp*1024 + q*4;
#pragma unroll
        for (int j = 0; j < 4; ++j)
            dst[j] = (float)__builtin_bit_cast(_Float16, (unsigned short)((w >> (16*j)) & 0xFFFF));
    }
    __syncthreads();

    // K projection: k[pp][j], j = jj*256+tid
    float kacc[4][4];
#pragma unroll
    for (int jj = 0; jj < 4; ++jj) {
        const float bkv = bk[jj*256 + tid];
#pragma unroll
        for (int pp = 0; pp < 4; ++pp) kacc[jj][pp] = bkv;
    }
    for (int e = 0; e < 1024; ++e) {
        float hvv[4];
#pragma unroll
        for (int pp = 0; pp < 4; ++pp) hvv[pp] = hv[pp*1024 + e];
#pragma unroll
        for (int jj = 0; jj < 4; ++jj) {
            const float w = (float)WkT[(size_t)e*1024 + jj*256 + tid];
#pragma unroll
            for (int pp = 0; pp < 4; ++pp) kacc[jj][pp] += w * hvv[pp];
        }
    }
#pragma unroll
    for (int jj = 0; jj < 4; ++jj)
#pragma unroll
        for (int pp = 0; pp < 4; ++pp)
            k16[pp*1024 + jj*256 + tid] = (_Float16)kacc[jj][pp];

    // Q head 15: one pair per 64-lane chunk
    {
        const int d = tid & 63, ph = tid >> 6;
        float a0 = bq[960 + d];
        for (int e = 0; e < 1024; ++e)
            a0 += (float)WqT[e*64 + d] * hv[ph*1024 + e];
        qb[ph*64 + d] = a0;
    }
    // vz[pp][kh]
    if (tid < 64) {
        const int pp = tid >> 4, kh = tid & 15;
        const int r = (p0 + pp) & 15;
        float a = cv[r*16 + kh];
        for (int e = 0; e < 1024; ++e)
            a += wv2[((size_t)r*1024 + e)*16 + kh] * hv[pp*1024 + e];
        vzb[pp*16 + kh] = a;
    }
    __syncthreads();
    if (tid < 64) {
        const int pp = tid >> 4, kh = tid & 15;
        float a = 0.f;
#pragma unroll
        for (int d = 0; d < 64; ++d)
            a += qb[pp*64 + d] * (float)k16[pp*1024 + kh*64 + d];
        scb[pp*16 + kh] = a * 0.125f;
    }
    __syncthreads();
    if (tid < 4) {
        const int base = tid*16;
        float m = scb[base];
        for (int kh = 1; kh < 16; ++kh) m = fmaxf(m, scb[base+kh]);
        float sum = 0.f, wz = 0.f;
        for (int kh = 0; kh < 16; ++kh) {
            const float pe = __expf(scb[base+kh] - m);
            sum += pe; wz += pe * vzb[base+kh];
        }
        atomicAdd(&logits[(p0 + tid) >> 4], wz / sum);
    }
    __syncthreads();
    if (tid == 0) {
        const unsigned old = __hip_atomic_fetch_add(cnts + 2, 1u, __ATOMIC_RELEASE, __HIP_MEMORY_SCOPE_AGENT);
        *lastf = (old == 127u) ? 1 : 0;
    }
    __syncthreads();
    if (*lastf) {
        if (tid < 32) {
            const float lg = AT_LD(logits + tid) + beff[0];
            out[tid] = 1.f/(1.f + __expf(-lg));
        }
    }
}

// -------------------- launcher --------------------

extern "C" void kernel_launch(void* const* d_in, const int* in_sizes, int n_in,
                              void* d_out, int out_size, void* d_ws, size_t ws_size,
                              hipStream_t stream)
{
    (void)in_sizes; (void)n_in; (void)out_size; (void)ws_size;
    const float* x    = (const float*)d_in[0];
    const float* Wihf = (const float*)d_in[1];
    const float* Whhf = (const float*)d_in[2];
    const float* b_f  = (const float*)d_in[3];
    const float* Wihb = (const float*)d_in[4];
    const float* Whhb = (const float*)d_in[5];
    const float* b_b  = (const float*)d_in[6];
    const float* Wq   = (const float*)d_in[7];
    const float* bq   = (const float*)d_in[8];
    const float* Wk   = (const float*)d_in[9];
    const float* bk   = (const float*)d_in[10];
    const float* Wv   = (const float*)d_in[11];
    const float* bv   = (const float*)d_in[12];
    const float* Wo   = (const float*)d_in[13];
    const float* bo   = (const float*)d_in[14];
    const float* Wfc  = (const float*)d_in[15];
    const float* bfc  = (const float*)d_in[16];
    char* ws = (char*)d_ws;
    float* out = (float*)d_out;

    // init: counters/logits/weff/beff/flags + h slot0 = 0; history slots = 0xFFFF
    hipMemsetAsync(ws, 0, OFF_HF + 32768, stream);                      // cnts..h_f[0]
    hipMemsetAsync(ws + OFF_HF + 32768, 0xFF, 512ull*32768, stream);    // h_f[1..512]
    hipMemsetAsync(ws + OFF_HB, 0, 32768, stream);                      // h_b[0]
    hipMemsetAsync(ws + OFF_HB + 32768, 0xFF, 16ull*32768, stream);     // h_b[1..16]

    hipLaunchKernelGGL(k_convert, dim3(512), dim3(256), 0, stream, Whhf, Wihf, Whhb, Wihb, ws);
    hipLaunchKernelGGL(k_weff,    dim3(64),  dim3(256), 0, stream, Wfc, Wo, bo, bfc, ws);
    hipLaunchKernelGGL(k_wv2,     dim3(65),  dim3(256), 0, stream, Wv, bv, ws);
    hipLaunchKernelGGL(k_tk,      dim3(1024),dim3(256), 0, stream, Wk, ws);
    hipLaunchKernelGGL(k_tq,      dim3(256), dim3(256), 0, stream, Wq, ws);
    hipLaunchKernelGGL(bilstm_main, dim3(128), dim3(256), DYN_LDS, stream,
                       x, b_f, b_b, bq, bk, ws, out);
}

// Round 7
// 1962.361 us; speedup vs baseline: 1.5192x; 1.5192x over previous
//
#include <hip/hip_runtime.h>
#include <cstdint>
#include <cstddef>

// B=32, S=512, I=256, H=512, E=1024, NH=16, HD=64
// Structural collapse (verified): only attention head 15 at s in [496,512)
// reaches the FC head; backward LSTM needs only its first 16 steps; Wo/Wfc
// fold to w_eff; w_eff-contracted Wv folds to wv2.
//
// Round 6: EXACT revert to the 1853us sentinel baseline (flag handshake
// regressed to 2680us: producer store-ack wait + chained flag->data loads
// added ~4300cyc/step; sc0/XCD variant regressed to 2133us). ONE addition:
// fire-and-forget PREWARM of slot t+1 during step t. Theory: the dominant
// per-step cost is cold-line write-allocate visibility latency -- h slots
// are 0xFF-memset, HBM-resident; the producer's sub-line agent store cannot
// become visible until the line is fetched from HBM (~1500-2500cy), and that
// sits on the serial critical path every step. Prewarm loads pull the t+1
// lines into LLC ~3us before the store arrives, so the store merges into a
// hot line (~300-600cy visibility). Loads cannot corrupt data (fetch only on
// miss; hits return newest), so sentinel semantics are untouched.

typedef _Float16 v8h __attribute__((ext_vector_type(8)));
typedef _Float16 v4h __attribute__((ext_vector_type(4)));
typedef float    v4f __attribute__((ext_vector_type(4)));

#define AT_LD(p)     __hip_atomic_load((p), __ATOMIC_RELAXED, __HIP_MEMORY_SCOPE_AGENT)
#define AT_ST(p, v)  __hip_atomic_store((p), (v), __ATOMIC_RELAXED, __HIP_MEMORY_SCOPE_AGENT)

// ---- workspace layout (bytes) ----
static constexpr size_t OFF_CNT   = 0;        // 3 x u32: lstm-done, -, epi-done
static constexpr size_t OFF_LOGIT = 256;      // 32 f32
static constexpr size_t OFF_BEFF  = 512;      // 1 f32
static constexpr size_t OFF_WEFF  = 1024;     // 1024 f32
static constexpr size_t OFF_HF    = 8192;     // h_f[513][32][512] f16 (slot = s+1)
static constexpr size_t HF_BYTES  = 513ull*32768;
static constexpr size_t OFF_HB    = OFF_HF + HF_BYTES;   // h_b[17][32][512] f16
static constexpr size_t HB_BYTES  = 17ull*32768;
static constexpr size_t OFF_WHHF  = OFF_HB + HB_BYTES;   // 2048x512 f16
static constexpr size_t OFF_WIHF  = OFF_WHHF + 2048ull*512*2;
static constexpr size_t OFF_WHHB  = OFF_WIHF + 2048ull*256*2;
static constexpr size_t OFF_WIHB  = OFF_WHHB + 2048ull*512*2;
static constexpr size_t OFF_WKT   = OFF_WIHB + 2048ull*256*2;   // 1024x1024 f16
static constexpr size_t OFF_WQT   = OFF_WKT + 1024ull*1024*2;   // 1024x64 f16
static constexpr size_t OFF_WV2   = OFF_WQT + 1024ull*64*2;     // 16*1024*16 f32
static constexpr size_t OFF_CV    = OFF_WV2 + 16ull*1024*16*4;  // 256 f32
// total ~25.7 MiB

static constexpr int PSTR    = 776;                 // panel stride (f16)
static constexpr int GSTR    = 68;                  // gates stride (f32)
static constexpr int LDS_PANEL_B = 16*PSTR*2;       // 24832
static constexpr int DYN_LDS = LDS_PANEL_B + 64*GSTR*4;  // 24832+17408 = 42240

__device__ __forceinline__ bool has_ffff(unsigned long long w) {
    return ((w & 0xFFFFull) == 0xFFFFull) ||
           (((w >> 16) & 0xFFFFull) == 0xFFFFull) ||
           (((w >> 32) & 0xFFFFull) == 0xFFFFull) ||
           ((w >> 48) == 0xFFFFull);
}

// -------------------- prep kernels --------------------

__global__ void k_convert(const float* __restrict__ whhf, const float* __restrict__ wihf,
                          const float* __restrict__ whhb, const float* __restrict__ wihb,
                          char* __restrict__ ws)
{
    _Float16* o1 = (_Float16*)(ws + OFF_WHHF);
    _Float16* o2 = (_Float16*)(ws + OFF_WIHF);
    _Float16* o3 = (_Float16*)(ws + OFF_WHHB);
    _Float16* o4 = (_Float16*)(ws + OFF_WIHB);
    const int stride = gridDim.x * blockDim.x;
    for (int i = blockIdx.x*blockDim.x + threadIdx.x; i < 2048*512; i += stride) {
        o1[i] = (_Float16)whhf[i];
        o3[i] = (_Float16)whhb[i];
    }
    for (int i = blockIdx.x*blockDim.x + threadIdx.x; i < 2048*256; i += stride) {
        o2[i] = (_Float16)wihf[i];
        o4[i] = (_Float16)wihb[i];
    }
}

// weff[e2] += partial(Wfc . Wo[:,e2]); beff += partial(Wfc . bo) (+bfc once)
__global__ void k_weff(const float* __restrict__ Wfc, const float* __restrict__ Wo,
                       const float* __restrict__ bo, const float* __restrict__ bfc,
                       char* __restrict__ ws)
{
    float* weff = (float*)(ws + OFF_WEFF);
    float* beff = (float*)(ws + OFF_BEFF);
    const int bid = blockIdx.x;                 // 64 blocks
    const int e2 = (bid & 3)*256 + threadIdx.x;
    const int slab = bid >> 2;                  // 16 slabs of 64 e
    float a = 0.f;
    for (int e = slab*64; e < slab*64 + 64; ++e)
        a += Wfc[e] * Wo[(size_t)e*1024 + e2];
    atomicAdd(weff + e2, a);
    if ((bid & 3) == 0 && threadIdx.x < 64) {
        const int e = slab*64 + threadIdx.x;
        float b = Wfc[e]*bo[e];
        if (bid == 0 && threadIdx.x == 0) b += bfc[0];
        atomicAdd(beff, b);
    }
}

// wv2[(r*1024+e)*16+kh] = sum_hd weff[r*64+hd]*Wv[(kh*64+hd)*1024+e]; cv
__global__ void k_wv2(const float* __restrict__ Wv, const float* __restrict__ bv,
                      char* __restrict__ ws)
{
    const float* weff = (const float*)(ws + OFF_WEFF);
    float* wv2 = (float*)(ws + OFF_WV2);
    float* cv  = (float*)(ws + OFF_CV);
    const int bid = blockIdx.x;                 // 65 blocks
    if (bid < 64) {
        const int r = bid >> 2;
        const int e = (bid & 3)*256 + threadIdx.x;
        for (int kh = 0; kh < 16; ++kh) {
            float a = 0.f;
            for (int hd = 0; hd < 64; ++hd)
                a += weff[r*64 + hd] * Wv[((size_t)(kh*64 + hd))*1024 + e];
            wv2[((size_t)r*1024 + e)*16 + kh] = a;
        }
    } else {
        const int r2 = threadIdx.x >> 4, k2 = threadIdx.x & 15;
        float a = 0.f;
        for (int hd = 0; hd < 64; ++hd)
            a += weff[r2*64 + hd] * bv[k2*64 + hd];
        cv[threadIdx.x] = a;
    }
}

// WkT[e][j] = Wk[j][e], fp16
__global__ void k_tk(const float* __restrict__ Wk, char* __restrict__ ws)
{
    _Float16* WkT = (_Float16*)(ws + OFF_WKT);
    __shared__ float tile[32][33];
    const int jt = blockIdx.x & 31, et = blockIdx.x >> 5;   // 1024 blocks
    const int tx = threadIdx.x & 31, ty = threadIdx.x >> 5; // 32x8
    for (int i = 0; i < 4; ++i)
        tile[ty + 8*i][tx] = Wk[((size_t)(jt*32 + ty + 8*i))*1024 + et*32 + tx];
    __syncthreads();
    for (int i = 0; i < 4; ++i)
        WkT[((size_t)(et*32 + ty + 8*i))*1024 + jt*32 + tx] = (_Float16)tile[tx][ty + 8*i];
}

// WqT15[e][d] = Wq[960+d][e], fp16
__global__ void k_tq(const float* __restrict__ Wq, char* __restrict__ ws)
{
    _Float16* WqT = (_Float16*)(ws + OFF_WQT);
    const int gid = blockIdx.x*256 + threadIdx.x;  // 256 blocks
    const int d = gid & 63, e = gid >> 6;
    WqT[e*64 + d] = (_Float16)Wq[((size_t)(960 + d))*1024 + e];
}

// -------------------- main persistent kernel --------------------
// 128 WGs x 256 threads. group g = wgid>>5 (8 batches), colgroup = wgid&31
// (16 h-cols). Phase 0: bwd 16 steps; phase 1: fwd 512 steps. Full h history
// (one fresh 32KB slot per step) pre-filled with 0xFFFF sentinel (impossible
// f16 output of og*tanh(c)); consumers poll the data itself via agent-scope
// atomic loads. Round 6 addition: prewarm slot t+1 during step t.

__global__ __launch_bounds__(256, 1)
void bilstm_main(const float* __restrict__ xg,
                 const float* __restrict__ b_f, const float* __restrict__ b_b,
                 const float* __restrict__ bq,  const float* __restrict__ bk,
                 char* __restrict__ ws, float* __restrict__ out)
{
    extern __shared__ char smem[];
    _Float16* panel = (_Float16*)smem;                   // [16][776]
    float* gates = (float*)(smem + LDS_PANEL_B);         // [64][68]

    const int tid  = threadIdx.x;
    const int wgid = blockIdx.x;
    const int wave = tid >> 6;
    const int lane = tid & 63;
    const int quad = lane >> 4;
    const int l16  = lane & 15;
    const int grp  = wgid >> 5;            // batch group (8 batches)
    const int col0 = (wgid & 31) * 16;

    unsigned* cnts  = (unsigned*)(ws + OFF_CNT);
    float*   logits = (float*)(ws + OFF_LOGIT);

    // activation role (tid < 128): batch b = tid>>4 in [0,8), col c = tid&15
    const int ac = tid & 15;
    const int ab = tid >> 4;

    for (int phase = 0; phase < 2; ++phase) {
        const int dir     = phase == 0 ? 1 : 0;       // bwd first
        const int nsteps  = dir ? 16 : 512;
        char* hslab = ws + (dir ? OFF_HB : OFF_HF);
        const _Float16* whh = (const _Float16*)(ws + (dir ? OFF_WHHB : OFF_WHHF));
        const _Float16* wih = (const _Float16*)(ws + (dir ? OFF_WIHB : OFF_WIHF));
        const float* bias = dir ? b_b : b_f;

        // persistent B fragments: rows (gate nt, col l16) x K=768, wave = K-quarter
        v8h bfrag[4][6];
#pragma unroll
        for (int nt = 0; nt < 4; ++nt)
#pragma unroll
            for (int kk = 0; kk < 6; ++kk) {
                const int kb = (wave*6 + kk)*32 + quad*8;
                const int r  = nt*512 + col0 + l16;
                const _Float16* src = (kb < 512) ? (whh + (size_t)r*512 + kb)
                                                 : (wih + (size_t)r*256 + (kb - 512));
                bfrag[nt][kk] = *(const v8h*)src;
            }
        float bia[4];
#pragma unroll
        for (int g = 0; g < 4; ++g) bia[g] = bias[g*512 + col0 + ac];

        float cst = 0.f;

        for (int t = 0; t < nsteps; ++t) {
            const int s = dir ? (511 - t) : t;

            // prefetch x[group batches][s][:] into registers
            float4 xv[2];
#pragma unroll
            for (int i = 0; i < 2; ++i) {
                const int ch = tid + 256*i;           // [0,512)
                const int b = ch >> 6, ic = ch & 63;
                xv[i] = *(const float4*)(xg + ((size_t)(grp*8 + b)*512 + s)*256 + ic*4);
            }

            // gather h_{t-1} (slot t) by polling the data sentinel
            {
                const int b = tid >> 5, seg = tid & 31;   // 8 KB: 8 b x 512 cols
                const unsigned long long* src = (const unsigned long long*)hslab
                    + (size_t)t*4096 + (size_t)(grp*8 + b)*128 + seg*4;
                unsigned long long w0, w1, w2, w3;
                for (;;) {
                    w0 = AT_LD(src + 0); w1 = AT_LD(src + 1);
                    w2 = AT_LD(src + 2); w3 = AT_LD(src + 3);
                    if (!(has_ffff(w0) || has_ffff(w1) || has_ffff(w2) || has_ffff(w3)))
                        break;
                    __builtin_amdgcn_s_sleep(1);
                }
                // prewarm slot t+1 (fire-and-forget, never waited here):
                // pulls the 0xFF-memset lines HBM->LLC ~one step before the
                // producers store, so their stores merge into hot lines.
                {
                    unsigned long long pw;
                    asm volatile("global_load_dwordx2 %0, %1, off"
                                 : "=v"(pw) : "v"(src + 4096));
                }
                unsigned long long* dst = (unsigned long long*)(panel + b*PSTR + seg*16);
                dst[0] = w0; dst[1] = w1; dst[2] = w2; dst[3] = w3;
            }
            // x (f32 regs -> f16) into panel cols [512,768)
#pragma unroll
            for (int i = 0; i < 2; ++i) {
                const int ch = tid + 256*i;
                const int b = ch >> 6, ic = ch & 63;
                v4h hx = { (_Float16)xv[i].x, (_Float16)xv[i].y,
                           (_Float16)xv[i].z, (_Float16)xv[i].w };
                *(v4h*)(panel + b*PSTR + 512 + ic*4) = hx;
            }
            __syncthreads();   // S_a: panel ready

            // GEMM: gates[b(8)][n(64)] = A[b][768] * W[n][768], K 4-way by wave
            v4f acc[4];
#pragma unroll
            for (int nt = 0; nt < 4; ++nt) { v4f z = {0.f,0.f,0.f,0.f}; acc[nt] = z; }
#pragma unroll
            for (int kk = 0; kk < 6; ++kk) {
                const int kb = (wave*6 + kk)*32 + quad*8;
                const v8h a0 = *(const v8h*)(panel + l16*PSTR + kb);
#pragma unroll
                for (int nt = 0; nt < 4; ++nt)
                    acc[nt] = __builtin_amdgcn_mfma_f32_16x16x32_f16(a0, bfrag[nt][kk], acc[nt], 0, 0, 0);
            }
            // K-partials (separate LDS region; panel reads complete before S_c)
#pragma unroll
            for (int nt = 0; nt < 4; ++nt)
#pragma unroll
                for (int r = 0; r < 4; ++r)
                    gates[(nt*16 + l16)*GSTR + (quad*4 + r)*4 + wave] = acc[nt][r];
            __syncthreads();   // S_c: partials ready

            // activations: tid<128, one (b, c) each
            if (tid < 128) {
                float g[4];
#pragma unroll
                for (int gi = 0; gi < 4; ++gi) {
                    const v4f v = *(const v4f*)(gates + (gi*16 + ac)*GSTR + ab*4);
                    g[gi] = v.x + v.y + v.z + v.w + bia[gi];
                }
                const float ig = 1.f/(1.f + __expf(-g[0]));
                const float fg = 1.f/(1.f + __expf(-g[1]));
                const float gg = 1.f - 2.f/(__expf(2.f*g[2]) + 1.f);
                const float og = 1.f/(1.f + __expf(-g[3]));
                cst = fg*cst + ig*gg;
                const float hn = og * (1.f - 2.f/(__expf(2.f*cst) + 1.f));
                const unsigned hb = (unsigned)__builtin_bit_cast(unsigned short, (_Float16)hn);
                const unsigned ot = (unsigned)__shfl_xor((int)hb, 1);
                if ((ac & 1) == 0) {
                    _Float16* hrow = (_Float16*)hslab
                        + ((size_t)(t+1)*32 + (grp*8 + ab))*512 + col0 + ac;
                    AT_ST((unsigned*)hrow, hb | (ot << 16));
                }
            }
            // no trailing barrier: next step's poll self-synchronizes
        }
    }

    // join before epilogue
    __syncthreads();
    if (tid == 0) {
        __hip_atomic_fetch_add(cnts + 0, 1u, __ATOMIC_RELAXED, __HIP_MEMORY_SCOPE_AGENT);
        while (AT_LD(cnts + 0) < 128u) __builtin_amdgcn_s_sleep(8);
    }
    __syncthreads();

    // ---------------- collapsed attention epilogue ----------------
    // 4 pairs per WG: p = wgid*4+pp -> (b = p>>4, r = p&15, s' = 496+r)
    float*    hv  = (float*)smem;                 // [4][1024]
    _Float16* k16 = (_Float16*)(smem + 16384);    // [4][1024]
    float*    qb  = (float*)(smem + 24576);       // [4][64]
    float*    vzb = (float*)(smem + 25600);       // [4][16]
    float*    scb = (float*)(smem + 25856);       // [4][16]
    int*      lastf = (int*)(smem + 26112);

    const _Float16* WkT = (const _Float16*)(ws + OFF_WKT);
    const _Float16* WqT = (const _Float16*)(ws + OFF_WQT);
    const float* wv2 = (const float*)(ws + OFF_WV2);
    const float* cv  = (const float*)(ws + OFF_CV);
    const float* beff= (const float*)(ws + OFF_BEFF);

    const int p0 = wgid * 4;
#pragma unroll
    for (int i = 0; i < 4; ++i) {
        const int ch = tid + 256*i;               // 1024 u64 chunks
        const int pp = ch >> 8, q = ch & 255;     // e = q*4
        const int p = p0 + pp; const int b = p >> 4; const int r = p & 15;
        unsigned long long w;
        if (q < 128)   // fwd h at s=496+r -> slot 497+r
            w = AT_LD((const unsigned long long*)(ws + OFF_HF)
                      + ((size_t)(497 + r)*32 + b)*128 + q);
        else           // bwd h at s=496+r -> slot 16-r
            w = AT_LD((const unsigned long long*)(ws + OFF_HB)
                      + ((size_t)(16 - r)*32 + b)*128 + (q - 128));
        float* dst = hv + pp*1024 + q*4;
#pragma unroll
        for (int j = 0; j < 4; ++j)
            dst[j] = (float)__builtin_bit_cast(_Float16, (unsigned short)((w >> (16*j)) & 0xFFFF));
    }
    __syncthreads();

    // K projection: k[pp][j], j = jj*256+tid
    float kacc[4][4];
#pragma unroll
    for (int jj = 0; jj < 4; ++jj) {
        const float bkv = bk[jj*256 + tid];
#pragma unroll
        for (int pp = 0; pp < 4; ++pp) kacc[jj][pp] = bkv;
    }
    for (int e = 0; e < 1024; ++e) {
        float hvv[4];
#pragma unroll
        for (int pp = 0; pp < 4; ++pp) hvv[pp] = hv[pp*1024 + e];
#pragma unroll
        for (int jj = 0; jj < 4; ++jj) {
            const float w = (float)WkT[(size_t)e*1024 + jj*256 + tid];
#pragma unroll
            for (int pp = 0; pp < 4; ++pp) kacc[jj][pp] += w * hvv[pp];
        }
    }
#pragma unroll
    for (int jj = 0; jj < 4; ++jj)
#pragma unroll
        for (int pp = 0; pp < 4; ++pp)
            k16[pp*1024 + jj*256 + tid] = (_Float16)kacc[jj][pp];

    // Q head 15: one pair per 64-lane chunk
    {
        const int d = tid & 63, ph = tid >> 6;
        float a0 = bq[960 + d];
        for (int e = 0; e < 1024; ++e)
            a0 += (float)WqT[e*64 + d] * hv[ph*1024 + e];
        qb[ph*64 + d] = a0;
    }
    // vz[pp][kh]
    if (tid < 64) {
        const int pp = tid >> 4, kh = tid & 15;
        const int r = (p0 + pp) & 15;
        float a = cv[r*16 + kh];
        for (int e = 0; e < 1024; ++e)
            a += wv2[((size_t)r*1024 + e)*16 + kh] * hv[pp*1024 + e];
        vzb[pp*16 + kh] = a;
    }
    __syncthreads();
    if (tid < 64) {
        const int pp = tid >> 4, kh = tid & 15;
        float a = 0.f;
#pragma unroll
        for (int d = 0; d < 64; ++d)
            a += qb[pp*64 + d] * (float)k16[pp*1024 + kh*64 + d];
        scb[pp*16 + kh] = a * 0.125f;
    }
    __syncthreads();
    if (tid < 4) {
        const int base = tid*16;
        float m = scb[base];
        for (int kh = 1; kh < 16; ++kh) m = fmaxf(m, scb[base+kh]);
        float sum = 0.f, wz = 0.f;
        for (int kh = 0; kh < 16; ++kh) {
            const float pe = __expf(scb[base+kh] - m);
            sum += pe; wz += pe * vzb[base+kh];
        }
        atomicAdd(&logits[(p0 + tid) >> 4], wz / sum);
    }
    __syncthreads();
    if (tid == 0) {
        const unsigned old = __hip_atomic_fetch_add(cnts + 2, 1u, __ATOMIC_RELAXED, __HIP_MEMORY_SCOPE_AGENT);
        *lastf = (old == 127u) ? 1 : 0;
    }
    __syncthreads();
    if (*lastf) {
        if (tid < 32) {
            const float lg = AT_LD(logits + tid) + beff[0];
            out[tid] = 1.f/(1.f + __expf(-lg));
        }
    }
}

// -------------------- launcher --------------------

extern "C" void kernel_launch(void* const* d_in, const int* in_sizes, int n_in,
                              void* d_out, int out_size, void* d_ws, size_t ws_size,
                              hipStream_t stream)
{
    (void)in_sizes; (void)n_in; (void)out_size; (void)ws_size;
    const float* x    = (const float*)d_in[0];
    const float* Wihf = (const float*)d_in[1];
    const float* Whhf = (const float*)d_in[2];
    const float* b_f  = (const float*)d_in[3];
    const float* Wihb = (const float*)d_in[4];
    const float* Whhb = (const float*)d_in[5];
    const float* b_b  = (const float*)d_in[6];
    const float* Wq   = (const float*)d_in[7];
    const float* bq   = (const float*)d_in[8];
    const float* Wk   = (const float*)d_in[9];
    const float* bk   = (const float*)d_in[10];
    const float* Wv   = (const float*)d_in[11];
    const float* bv   = (const float*)d_in[12];
    const float* Wo   = (const float*)d_in[13];
    const float* bo   = (const float*)d_in[14];
    const float* Wfc  = (const float*)d_in[15];
    const float* bfc  = (const float*)d_in[16];
    char* ws = (char*)d_ws;
    float* out = (float*)d_out;

    // init: counters/logits/weff/beff + h slot0 = 0; history slots = 0xFFFF sentinel
    hipMemsetAsync(ws, 0, OFF_HF + 32768, stream);                      // cnts..h_f[0]
    hipMemsetAsync(ws + OFF_HF + 32768, 0xFF, 512ull*32768, stream);    // h_f[1..512]
    hipMemsetAsync(ws + OFF_HB, 0, 32768, stream);                      // h_b[0]
    hipMemsetAsync(ws + OFF_HB + 32768, 0xFF, 16ull*32768, stream);     // h_b[1..16]

    hipLaunchKernelGGL(k_convert, dim3(512), dim3(256), 0, stream, Whhf, Wihf, Whhb, Wihb, ws);
    hipLaunchKernelGGL(k_weff,    dim3(64),  dim3(256), 0, stream, Wfc, Wo, bo, bfc, ws);
    hipLaunchKernelGGL(k_wv2,     dim3(65),  dim3(256), 0, stream, Wv, bv, ws);
    hipLaunchKernelGGL(k_tk,      dim3(1024),dim3(256), 0, stream, Wk, ws);
    hipLaunchKernelGGL(k_tq,      dim3(256), dim3(256), 0, stream, Wq, ws);
    hipLaunchKernelGGL(bilstm_main, dim3(128), dim3(256), DYN_LDS, stream,
                       x, b_f, b_b, bq, bk, ws, out);
}

// Round 8
// 1927.364 us; speedup vs baseline: 1.5468x; 1.0182x over previous
//
#include <hip/hip_runtime.h>
#include <cstdint>
#include <cstddef>

// B=32, S=512, I=256, H=512, E=1024, NH=16, HD=64
// Structural collapse (verified): only attention head 15 at s in [496,512)
// reaches the FC head; backward LSTM needs only its first 16 steps; Wo/Wfc
// fold to w_eff; w_eff-contracted Wv folds to wv2.
//
// Round 8: prewarm removed (R7: FETCH tripled to 274MB, bench 1962 vs 1853
// baseline -- consumer polls already warm the lines; prewarm was redundant
// traffic). ONE new change: gather thread remap (b=tid&7, seg=tid>>3) to
// kill the 8-way LDS bank conflict on the panel h-writes (old mapping put
// 32 lanes of a half-wave at 32B stride in one b-row -> banks {0,8,16,24}
// only; SQ_LDS_BANK_CONFLICT = 4.79e7 = 709 cyc/WG/step on the critical
// path). New mapping: bank = 4b + 8(seg&3) -> all 32 banks, 2 lanes/bank
// (free). Wave-level global coalescing preserved (same 32 lines/wave).

typedef _Float16 v8h __attribute__((ext_vector_type(8)));
typedef _Float16 v4h __attribute__((ext_vector_type(4)));
typedef float    v4f __attribute__((ext_vector_type(4)));

#define AT_LD(p)     __hip_atomic_load((p), __ATOMIC_RELAXED, __HIP_MEMORY_SCOPE_AGENT)
#define AT_ST(p, v)  __hip_atomic_store((p), (v), __ATOMIC_RELAXED, __HIP_MEMORY_SCOPE_AGENT)

// ---- workspace layout (bytes) ----
static constexpr size_t OFF_CNT   = 0;        // 3 x u32: lstm-done, -, epi-done
static constexpr size_t OFF_LOGIT = 256;      // 32 f32
static constexpr size_t OFF_BEFF  = 512;      // 1 f32
static constexpr size_t OFF_WEFF  = 1024;     // 1024 f32
static constexpr size_t OFF_HF    = 8192;     // h_f[513][32][512] f16 (slot = s+1)
static constexpr size_t HF_BYTES  = 513ull*32768;
static constexpr size_t OFF_HB    = OFF_HF + HF_BYTES;   // h_b[17][32][512] f16
static constexpr size_t HB_BYTES  = 17ull*32768;
static constexpr size_t OFF_WHHF  = OFF_HB + HB_BYTES;   // 2048x512 f16
static constexpr size_t OFF_WIHF  = OFF_WHHF + 2048ull*512*2;
static constexpr size_t OFF_WHHB  = OFF_WIHF + 2048ull*256*2;
static constexpr size_t OFF_WIHB  = OFF_WHHB + 2048ull*512*2;
static constexpr size_t OFF_WKT   = OFF_WIHB + 2048ull*256*2;   // 1024x1024 f16
static constexpr size_t OFF_WQT   = OFF_WKT + 1024ull*1024*2;   // 1024x64 f16
static constexpr size_t OFF_WV2   = OFF_WQT + 1024ull*64*2;     // 16*1024*16 f32
static constexpr size_t OFF_CV    = OFF_WV2 + 16ull*1024*16*4;  // 256 f32
// total ~25.7 MiB

static constexpr int PSTR    = 776;                 // panel stride (f16)
static constexpr int GSTR    = 68;                  // gates stride (f32)
static constexpr int LDS_PANEL_B = 16*PSTR*2;       // 24832
static constexpr int DYN_LDS = LDS_PANEL_B + 64*GSTR*4;  // 24832+17408 = 42240

__device__ __forceinline__ bool has_ffff(unsigned long long w) {
    return ((w & 0xFFFFull) == 0xFFFFull) ||
           (((w >> 16) & 0xFFFFull) == 0xFFFFull) ||
           (((w >> 32) & 0xFFFFull) == 0xFFFFull) ||
           ((w >> 48) == 0xFFFFull);
}

// -------------------- prep kernels --------------------

__global__ void k_convert(const float* __restrict__ whhf, const float* __restrict__ wihf,
                          const float* __restrict__ whhb, const float* __restrict__ wihb,
                          char* __restrict__ ws)
{
    _Float16* o1 = (_Float16*)(ws + OFF_WHHF);
    _Float16* o2 = (_Float16*)(ws + OFF_WIHF);
    _Float16* o3 = (_Float16*)(ws + OFF_WHHB);
    _Float16* o4 = (_Float16*)(ws + OFF_WIHB);
    const int stride = gridDim.x * blockDim.x;
    for (int i = blockIdx.x*blockDim.x + threadIdx.x; i < 2048*512; i += stride) {
        o1[i] = (_Float16)whhf[i];
        o3[i] = (_Float16)whhb[i];
    }
    for (int i = blockIdx.x*blockDim.x + threadIdx.x; i < 2048*256; i += stride) {
        o2[i] = (_Float16)wihf[i];
        o4[i] = (_Float16)wihb[i];
    }
}

// weff[e2] += partial(Wfc . Wo[:,e2]); beff += partial(Wfc . bo) (+bfc once)
__global__ void k_weff(const float* __restrict__ Wfc, const float* __restrict__ Wo,
                       const float* __restrict__ bo, const float* __restrict__ bfc,
                       char* __restrict__ ws)
{
    float* weff = (float*)(ws + OFF_WEFF);
    float* beff = (float*)(ws + OFF_BEFF);
    const int bid = blockIdx.x;                 // 64 blocks
    const int e2 = (bid & 3)*256 + threadIdx.x;
    const int slab = bid >> 2;                  // 16 slabs of 64 e
    float a = 0.f;
    for (int e = slab*64; e < slab*64 + 64; ++e)
        a += Wfc[e] * Wo[(size_t)e*1024 + e2];
    atomicAdd(weff + e2, a);
    if ((bid & 3) == 0 && threadIdx.x < 64) {
        const int e = slab*64 + threadIdx.x;
        float b = Wfc[e]*bo[e];
        if (bid == 0 && threadIdx.x == 0) b += bfc[0];
        atomicAdd(beff, b);
    }
}

// wv2[(r*1024+e)*16+kh] = sum_hd weff[r*64+hd]*Wv[(kh*64+hd)*1024+e]; cv
__global__ void k_wv2(const float* __restrict__ Wv, const float* __restrict__ bv,
                      char* __restrict__ ws)
{
    const float* weff = (const float*)(ws + OFF_WEFF);
    float* wv2 = (float*)(ws + OFF_WV2);
    float* cv  = (float*)(ws + OFF_CV);
    const int bid = blockIdx.x;                 // 65 blocks
    if (bid < 64) {
        const int r = bid >> 2;
        const int e = (bid & 3)*256 + threadIdx.x;
        for (int kh = 0; kh < 16; ++kh) {
            float a = 0.f;
            for (int hd = 0; hd < 64; ++hd)
                a += weff[r*64 + hd] * Wv[((size_t)(kh*64 + hd))*1024 + e];
            wv2[((size_t)r*1024 + e)*16 + kh] = a;
        }
    } else {
        const int r2 = threadIdx.x >> 4, k2 = threadIdx.x & 15;
        float a = 0.f;
        for (int hd = 0; hd < 64; ++hd)
            a += weff[r2*64 + hd] * bv[k2*64 + hd];
        cv[threadIdx.x] = a;
    }
}

// WkT[e][j] = Wk[j][e], fp16
__global__ void k_tk(const float* __restrict__ Wk, char* __restrict__ ws)
{
    _Float16* WkT = (_Float16*)(ws + OFF_WKT);
    __shared__ float tile[32][33];
    const int jt = blockIdx.x & 31, et = blockIdx.x >> 5;   // 1024 blocks
    const int tx = threadIdx.x & 31, ty = threadIdx.x >> 5; // 32x8
    for (int i = 0; i < 4; ++i)
        tile[ty + 8*i][tx] = Wk[((size_t)(jt*32 + ty + 8*i))*1024 + et*32 + tx];
    __syncthreads();
    for (int i = 0; i < 4; ++i)
        WkT[((size_t)(et*32 + ty + 8*i))*1024 + jt*32 + tx] = (_Float16)tile[tx][ty + 8*i];
}

// WqT15[e][d] = Wq[960+d][e], fp16
__global__ void k_tq(const float* __restrict__ Wq, char* __restrict__ ws)
{
    _Float16* WqT = (_Float16*)(ws + OFF_WQT);
    const int gid = blockIdx.x*256 + threadIdx.x;  // 256 blocks
    const int d = gid & 63, e = gid >> 6;
    WqT[e*64 + d] = (_Float16)Wq[((size_t)(960 + d))*1024 + e];
}

// -------------------- main persistent kernel --------------------
// 128 WGs x 256 threads. group g = wgid>>5 (8 batches), colgroup = wgid&31
// (16 h-cols). Phase 0: bwd 16 steps; phase 1: fwd 512 steps. Full h history
// (one fresh 32KB slot per step) pre-filled with 0xFFFF sentinel (impossible
// f16 output of og*tanh(c)); consumers poll the data itself via agent-scope
// atomic loads. Round 8: bank-conflict-free gather mapping.

__global__ __launch_bounds__(256, 1)
void bilstm_main(const float* __restrict__ xg,
                 const float* __restrict__ b_f, const float* __restrict__ b_b,
                 const float* __restrict__ bq,  const float* __restrict__ bk,
                 char* __restrict__ ws, float* __restrict__ out)
{
    extern __shared__ char smem[];
    _Float16* panel = (_Float16*)smem;                   // [16][776]
    float* gates = (float*)(smem + LDS_PANEL_B);         // [64][68]

    const int tid  = threadIdx.x;
    const int wgid = blockIdx.x;
    const int wave = tid >> 6;
    const int lane = tid & 63;
    const int quad = lane >> 4;
    const int l16  = lane & 15;
    const int grp  = wgid >> 5;            // batch group (8 batches)
    const int col0 = (wgid & 31) * 16;

    unsigned* cnts  = (unsigned*)(ws + OFF_CNT);
    float*   logits = (float*)(ws + OFF_LOGIT);

    // activation role (tid < 128): batch b = tid>>4 in [0,8), col c = tid&15
    const int ac = tid & 15;
    const int ab = tid >> 4;

    for (int phase = 0; phase < 2; ++phase) {
        const int dir     = phase == 0 ? 1 : 0;       // bwd first
        const int nsteps  = dir ? 16 : 512;
        char* hslab = ws + (dir ? OFF_HB : OFF_HF);
        const _Float16* whh = (const _Float16*)(ws + (dir ? OFF_WHHB : OFF_WHHF));
        const _Float16* wih = (const _Float16*)(ws + (dir ? OFF_WIHB : OFF_WIHF));
        const float* bias = dir ? b_b : b_f;

        // persistent B fragments: rows (gate nt, col l16) x K=768, wave = K-quarter
        v8h bfrag[4][6];
#pragma unroll
        for (int nt = 0; nt < 4; ++nt)
#pragma unroll
            for (int kk = 0; kk < 6; ++kk) {
                const int kb = (wave*6 + kk)*32 + quad*8;
                const int r  = nt*512 + col0 + l16;
                const _Float16* src = (kb < 512) ? (whh + (size_t)r*512 + kb)
                                                 : (wih + (size_t)r*256 + (kb - 512));
                bfrag[nt][kk] = *(const v8h*)src;
            }
        float bia[4];
#pragma unroll
        for (int g = 0; g < 4; ++g) bia[g] = bias[g*512 + col0 + ac];

        float cst = 0.f;

        for (int t = 0; t < nsteps; ++t) {
            const int s = dir ? (511 - t) : t;

            // prefetch x[group batches][s][:] into registers
            float4 xv[2];
#pragma unroll
            for (int i = 0; i < 2; ++i) {
                const int ch = tid + 256*i;           // [0,512)
                const int b = ch >> 6, ic = ch & 63;
                xv[i] = *(const float4*)(xg + ((size_t)(grp*8 + b)*512 + s)*256 + ic*4);
            }

            // gather h_{t-1} (slot t) by polling the data sentinel.
            // Mapping b=tid&7, seg=tid>>3: LDS write banks = 4b + 8(seg&3)
            // cover all 32 banks (2 lanes/bank, free) vs old 8-way conflict.
            {
                const int b = tid & 7, seg = tid >> 3;   // 8 KB: 8 b x 512 cols
                const unsigned long long* src = (const unsigned long long*)hslab
                    + (size_t)t*4096 + (size_t)(grp*8 + b)*128 + seg*4;
                unsigned long long w0, w1, w2, w3;
                for (;;) {
                    w0 = AT_LD(src + 0); w1 = AT_LD(src + 1);
                    w2 = AT_LD(src + 2); w3 = AT_LD(src + 3);
                    if (!(has_ffff(w0) || has_ffff(w1) || has_ffff(w2) || has_ffff(w3)))
                        break;
                    __builtin_amdgcn_s_sleep(1);
                }
                unsigned long long* dst = (unsigned long long*)(panel + b*PSTR + seg*16);
                dst[0] = w0; dst[1] = w1; dst[2] = w2; dst[3] = w3;
            }
            // x (f32 regs -> f16) into panel cols [512,768)
#pragma unroll
            for (int i = 0; i < 2; ++i) {
                const int ch = tid + 256*i;
                const int b = ch >> 6, ic = ch & 63;
                v4h hx = { (_Float16)xv[i].x, (_Float16)xv[i].y,
                           (_Float16)xv[i].z, (_Float16)xv[i].w };
                *(v4h*)(panel + b*PSTR + 512 + ic*4) = hx;
            }
            __syncthreads();   // S_a: panel ready

            // GEMM: gates[b(8)][n(64)] = A[b][768] * W[n][768], K 4-way by wave
            v4f acc[4];
#pragma unroll
            for (int nt = 0; nt < 4; ++nt) { v4f z = {0.f,0.f,0.f,0.f}; acc[nt] = z; }
#pragma unroll
            for (int kk = 0; kk < 6; ++kk) {
                const int kb = (wave*6 + kk)*32 + quad*8;
                const v8h a0 = *(const v8h*)(panel + l16*PSTR + kb);
#pragma unroll
                for (int nt = 0; nt < 4; ++nt)
                    acc[nt] = __builtin_amdgcn_mfma_f32_16x16x32_f16(a0, bfrag[nt][kk], acc[nt], 0, 0, 0);
            }
            // K-partials (separate LDS region; panel reads complete before S_c)
#pragma unroll
            for (int nt = 0; nt < 4; ++nt)
#pragma unroll
                for (int r = 0; r < 4; ++r)
                    gates[(nt*16 + l16)*GSTR + (quad*4 + r)*4 + wave] = acc[nt][r];
            __syncthreads();   // S_c: partials ready

            // activations: tid<128, one (b, c) each
            if (tid < 128) {
                float g[4];
#pragma unroll
                for (int gi = 0; gi < 4; ++gi) {
                    const v4f v = *(const v4f*)(gates + (gi*16 + ac)*GSTR + ab*4);
                    g[gi] = v.x + v.y + v.z + v.w + bia[gi];
                }
                const float ig = 1.f/(1.f + __expf(-g[0]));
                const float fg = 1.f/(1.f + __expf(-g[1]));
                const float gg = 1.f - 2.f/(__expf(2.f*g[2]) + 1.f);
                const float og = 1.f/(1.f + __expf(-g[3]));
                cst = fg*cst + ig*gg;
                const float hn = og * (1.f - 2.f/(__expf(2.f*cst) + 1.f));
                const unsigned hb = (unsigned)__builtin_bit_cast(unsigned short, (_Float16)hn);
                const unsigned ot = (unsigned)__shfl_xor((int)hb, 1);
                if ((ac & 1) == 0) {
                    _Float16* hrow = (_Float16*)hslab
                        + ((size_t)(t+1)*32 + (grp*8 + ab))*512 + col0 + ac;
                    AT_ST((unsigned*)hrow, hb | (ot << 16));
                }
            }
            // no trailing barrier: next step's poll self-synchronizes
        }
    }

    // join before epilogue
    __syncthreads();
    if (tid == 0) {
        __hip_atomic_fetch_add(cnts + 0, 1u, __ATOMIC_RELAXED, __HIP_MEMORY_SCOPE_AGENT);
        while (AT_LD(cnts + 0) < 128u) __builtin_amdgcn_s_sleep(8);
    }
    __syncthreads();

    // ---------------- collapsed attention epilogue ----------------
    // 4 pairs per WG: p = wgid*4+pp -> (b = p>>4, r = p&15, s' = 496+r)
    float*    hv  = (float*)smem;                 // [4][1024]
    _Float16* k16 = (_Float16*)(smem + 16384);    // [4][1024]
    float*    qb  = (float*)(smem + 24576);       // [4][64]
    float*    vzb = (float*)(smem + 25600);       // [4][16]
    float*    scb = (float*)(smem + 25856);       // [4][16]
    int*      lastf = (int*)(smem + 26112);

    const _Float16* WkT = (const _Float16*)(ws + OFF_WKT);
    const _Float16* WqT = (const _Float16*)(ws + OFF_WQT);
    const float* wv2 = (const float*)(ws + OFF_WV2);
    const float* cv  = (const float*)(ws + OFF_CV);
    const float* beff= (const float*)(ws + OFF_BEFF);

    const int p0 = wgid * 4;
#pragma unroll
    for (int i = 0; i < 4; ++i) {
        const int ch = tid + 256*i;               // 1024 u64 chunks
        const int pp = ch >> 8, q = ch & 255;     // e = q*4
        const int p = p0 + pp; const int b = p >> 4; const int r = p & 15;
        unsigned long long w;
        if (q < 128)   // fwd h at s=496+r -> slot 497+r
            w = AT_LD((const unsigned long long*)(ws + OFF_HF)
                      + ((size_t)(497 + r)*32 + b)*128 + q);
        else           // bwd h at s=496+r -> slot 16-r
            w = AT_LD((const unsigned long long*)(ws + OFF_HB)
                      + ((size_t)(16 - r)*32 + b)*128 + (q - 128));
        float* dst = hv + pp*1024 + q*4;
#pragma unroll
        for (int j = 0; j < 4; ++j)
            dst[j] = (float)__builtin_bit_cast(_Float16, (unsigned short)((w >> (16*j)) & 0xFFFF));
    }
    __syncthreads();

    // K projection: k[pp][j], j = jj*256+tid
    float kacc[4][4];
#pragma unroll
    for (int jj = 0; jj < 4; ++jj) {
        const float bkv = bk[jj*256 + tid];
#pragma unroll
        for (int pp = 0; pp < 4; ++pp) kacc[jj][pp] = bkv;
    }
    for (int e = 0; e < 1024; ++e) {
        float hvv[4];
#pragma unroll
        for (int pp = 0; pp < 4; ++pp) hvv[pp] = hv[pp*1024 + e];
#pragma unroll
        for (int jj = 0; jj < 4; ++jj) {
            const float w = (float)WkT[(size_t)e*1024 + jj*256 + tid];
#pragma unroll
            for (int pp = 0; pp < 4; ++pp) kacc[jj][pp] += w * hvv[pp];
        }
    }
#pragma unroll
    for (int jj = 0; jj < 4; ++jj)
#pragma unroll
        for (int pp = 0; pp < 4; ++pp)
            k16[pp*1024 + jj*256 + tid] = (_Float16)kacc[jj][pp];

    // Q head 15: one pair per 64-lane chunk
    {
        const int d = tid & 63, ph = tid >> 6;
        float a0 = bq[960 + d];
        for (int e = 0; e < 1024; ++e)
            a0 += (float)WqT[e*64 + d] * hv[ph*1024 + e];
        qb[ph*64 + d] = a0;
    }
    // vz[pp][kh]
    if (tid < 64) {
        const int pp = tid >> 4, kh = tid & 15;
        const int r = (p0 + pp) & 15;
        float a = cv[r*16 + kh];
        for (int e = 0; e < 1024; ++e)
            a += wv2[((size_t)r*1024 + e)*16 + kh] * hv[pp*1024 + e];
        vzb[pp*16 + kh] = a;
    }
    __syncthreads();
    if (tid < 64) {
        const int pp = tid >> 4, kh = tid & 15;
        float a = 0.f;
#pragma unroll
        for (int d = 0; d < 64; ++d)
            a += qb[pp*64 + d] * (float)k16[pp*1024 + kh*64 + d];
        scb[pp*16 + kh] = a * 0.125f;
    }
    __syncthreads();
    if (tid < 4) {
        const int base = tid*16;
        float m = scb[base];
        for (int kh = 1; kh < 16; ++kh) m = fmaxf(m, scb[base+kh]);
        float sum = 0.f, wz = 0.f;
        for (int kh = 0; kh < 16; ++kh) {
            const float pe = __expf(scb[base+kh] - m);
            sum += pe; wz += pe * vzb[base+kh];
        }
        atomicAdd(&logits[(p0 + tid) >> 4], wz / sum);
    }
    __syncthreads();
    if (tid == 0) {
        const unsigned old = __hip_atomic_fetch_add(cnts + 2, 1u, __ATOMIC_RELAXED, __HIP_MEMORY_SCOPE_AGENT);
        *lastf = (old == 127u) ? 1 : 0;
    }
    __syncthreads();
    if (*lastf) {
        if (tid < 32) {
            const float lg = AT_LD(logits + tid) + beff[0];
            out[tid] = 1.f/(1.f + __expf(-lg));
        }
    }
}

// -------------------- launcher --------------------

extern "C" void kernel_launch(void* const* d_in, const int* in_sizes, int n_in,
                              void* d_out, int out_size, void* d_ws, size_t ws_size,
                              hipStream_t stream)
{
    (void)in_sizes; (void)n_in; (void)out_size; (void)ws_size;
    const float* x    = (const float*)d_in[0];
    const float* Wihf = (const float*)d_in[1];
    const float* Whhf = (const float*)d_in[2];
    const float* b_f  = (const float*)d_in[3];
    const float* Wihb = (const float*)d_in[4];
    const float* Whhb = (const float*)d_in[5];
    const float* b_b  = (const float*)d_in[6];
    const float* Wq   = (const float*)d_in[7];
    const float* bq   = (const float*)d_in[8];
    const float* Wk   = (const float*)d_in[9];
    const float* bk   = (const float*)d_in[10];
    const float* Wv   = (const float*)d_in[11];
    const float* bv   = (const float*)d_in[12];
    const float* Wo   = (const float*)d_in[13];
    const float* bo   = (const float*)d_in[14];
    const float* Wfc  = (const float*)d_in[15];
    const float* bfc  = (const float*)d_in[16];
    char* ws = (char*)d_ws;
    float* out = (float*)d_out;

    // init: counters/logits/weff/beff + h slot0 = 0; history slots = 0xFFFF sentinel
    hipMemsetAsync(ws, 0, OFF_HF + 32768, stream);                      // cnts..h_f[0]
    hipMemsetAsync(ws + OFF_HF + 32768, 0xFF, 512ull*32768, stream);    // h_f[1..512]
    hipMemsetAsync(ws + OFF_HB, 0, 32768, stream);                      // h_b[0]
    hipMemsetAsync(ws + OFF_HB + 32768, 0xFF, 16ull*32768, stream);     // h_b[1..16]

    hipLaunchKernelGGL(k_convert, dim3(512), dim3(256), 0, stream, Whhf, Wihf, Whhb, Wihb, ws);
    hipLaunchKernelGGL(k_weff,    dim3(64),  dim3(256), 0, stream, Wfc, Wo, bo, bfc, ws);
    hipLaunchKernelGGL(k_wv2,     dim3(65),  dim3(256), 0, stream, Wv, bv, ws);
    hipLaunchKernelGGL(k_tk,      dim3(1024),dim3(256), 0, stream, Wk, ws);
    hipLaunchKernelGGL(k_tq,      dim3(256), dim3(256), 0, stream, Wq, ws);
    hipLaunchKernelGGL(bilstm_main, dim3(128), dim3(256), DYN_LDS, stream,
                       x, b_f, b_b, bq, bk, ws, out);
}